// Round 12
// baseline (160.898 us; speedup 1.0000x reference)
//
#include <hip/hip_runtime.h>
#include <math.h>

#define N_EL    16
#define N_NUC   4
#define N_FEATS 32
#define N_PAIRS 184
#define HIDDEN  64
#define TB      32           // batch elements per block
#define BLOCK   256
#define DLD     185          // dist LDS stride
#define H1LD    68           // h1 stride (inside reused dist region)
#define KP      46           // pairs per K-wave (4*46 = 184)

typedef _Float16 half8  __attribute__((ext_vector_type(8)));
typedef __fp16   fp16x2 __attribute__((ext_vector_type(2)));  // cvt_pkrtz ret type
typedef float    floatx16 __attribute__((ext_vector_type(16)));

// R11 post-mortem: __has_builtin-guarded __builtin_amdgcn_exp2f may silently
// fall back to OCML exp2f (~6-10 instrs with range fixup) — suspected source
// of the 3x VALU-issue anomaly (measured 48% VALUBusy vs ~16% hand-counted).
// Inline asm guarantees a single bare v_exp_f32 (HW-interlocked on CDNA).
__device__ __forceinline__ float exp2_raw(float x) {
    float r;
    asm("v_exp_f32 %0, %1" : "=v"(r) : "v"(x));
    return r;
}

// triu_indices(16, 1)
__constant__ unsigned char c_I[120] = {
    0,0,0,0,0,0,0,0,0,0,0,0,0,0,0,
    1,1,1,1,1,1,1,1,1,1,1,1,1,1,
    2,2,2,2,2,2,2,2,2,2,2,2,2,
    3,3,3,3,3,3,3,3,3,3,3,3,
    4,4,4,4,4,4,4,4,4,4,4,
    5,5,5,5,5,5,5,5,5,5,
    6,6,6,6,6,6,6,6,6,
    7,7,7,7,7,7,7,7,
    8,8,8,8,8,8,8,
    9,9,9,9,9,9,
    10,10,10,10,10,
    11,11,11,11,
    12,12,12,
    13,13,
    14
};
__constant__ unsigned char c_J[120] = {
    1,2,3,4,5,6,7,8,9,10,11,12,13,14,15,
    2,3,4,5,6,7,8,9,10,11,12,13,14,15,
    3,4,5,6,7,8,9,10,11,12,13,14,15,
    4,5,6,7,8,9,10,11,12,13,14,15,
    5,6,7,8,9,10,11,12,13,14,15,
    6,7,8,9,10,11,12,13,14,15,
    7,8,9,10,11,12,13,14,15,
    8,9,10,11,12,13,14,15,
    9,10,11,12,13,14,15,
    10,11,12,13,14,15,
    11,12,13,14,15,
    12,13,14,15,
    13,14,15,
    14,15,
    15
};

__device__ __forceinline__ float ssp(float x) {
    float a = fabsf(x);
    return fmaxf(x, 0.0f) + log1pf(__expf(-a)) - 0.69314718056f;
}
__device__ __forceinline__ float redg(float v) {
    v += __shfl_xor(v, 1);
    v += __shfl_xor(v, 2);
    v += __shfl_xor(v, 4);
    return v;
}

// ---------------------------------------------------------------------------
// Prep: one block per pair. Coalesced 8 KB load of W1[pair] into LDS, then
// each thread assembles one 16 B B-fragment chunk (conflict-free reads).
// Chunk id = p*256 + (kb*2+nh)*64 + lane; holds
// B[k = kb*16 + (lane>>5)*8 + j][n = nh*32 + (lane&31)], j = 0..7.
// ---------------------------------------------------------------------------
__global__ __launch_bounds__(256)
void prep_w1_kernel(const float* __restrict__ W1, half8* __restrict__ ws)
{
    __shared__ float w[N_FEATS * HIDDEN];   // 8 KB: one pair's rows
    const int p = blockIdx.x;
    const float* src = W1 + (size_t)p * (N_FEATS * HIDDEN);
    for (int k = threadIdx.x; k < N_FEATS * HIDDEN; k += 256) w[k] = src[k];
    __syncthreads();

    const int tid  = threadIdx.x;
    const int lane = tid & 63;
    const int cidx = tid >> 6;              // kb*2 + nh
    const int nh = cidx & 1, kb = cidx >> 1;
    const int krow = kb * 16 + (lane >> 5) * 8;
    const int n    = nh * 32 + (lane & 31);
    half8 h;
#pragma unroll
    for (int j = 0; j < 8; ++j) h[j] = (_Float16)w[(krow + j) * 64 + n];
    ws[(size_t)p * 256 + tid] = h;
}

// ---------------------------------------------------------------------------
// Main: block = 32 elements, 4 waves; wave kh owns all 32 el x 64 cols over
// pairs [kh*46, kh*46+46). K-loop unrolled x2 with two named fragment sets
// (no per-round register rotation). Only change vs R11: exp via inline-asm
// v_exp_f32 (single-variable A/B on the OCML-fallback theory).
// ---------------------------------------------------------------------------
__global__ __launch_bounds__(BLOCK)
void wfnet_kernel(const float* __restrict__ rs,
                  const float* __restrict__ coords,
                  const float* __restrict__ charges,
                  const half8* __restrict__ ws,
                  const float* __restrict__ b1,
                  const float* __restrict__ W2,
                  const float* __restrict__ b2,
                  const float* __restrict__ W3,
                  const float* __restrict__ b3,
                  float* __restrict__ out)
{
    __shared__ float lds_rs[TB * N_EL * 3];   // 6 KB
    __shared__ float lds_dist[TB * DLD];      // 23.7 KB; reused as red/h1 later

    const int tid  = threadIdx.x;
    const int wave = tid >> 6;               // = kh
    const int lane = tid & 63;
    const int m    = lane & 31;              // element row
    const int lh   = lane >> 5;              // k-half within fragment

    // ---- phase 1: stage rs ----
    {
        const float* rs_blk = rs + (size_t)blockIdx.x * (TB * N_EL * 3);
        for (int k = tid; k < TB * N_EL * 3; k += BLOCK) lds_rs[k] = rs_blk[k];
    }
    __syncthreads();

    // ---- phase 2: distances -> lds_dist; asy partial stays in a register ----
    float asy = 0.0f;
    {
        const int bl = tid >> 3, g = tid & 7;
        const float* myrs = lds_rs + bl * (N_EL * 3);
        float* dst = lds_dist + bl * DLD;
        const float4 ch = *(const float4*)charges;
        for (int i = 0; i < 8; ++i) {
            const int p = g + 8 * i;
            const int e = p >> 2, n = p & 3;
            const float dx = myrs[e * 3 + 0] - coords[n * 3 + 0];
            const float dy = myrs[e * 3 + 1] - coords[n * 3 + 1];
            const float dz = myrs[e * 3 + 2] - coords[n * 3 + 2];
            const float d = sqrtf(dx * dx + dy * dy + dz * dz);
            dst[p] = d;
            const float Z = (n < 2) ? ((n == 0) ? ch.x : ch.y)
                                    : ((n == 2) ? ch.z : ch.w);
            asy += (Z * d + d * d) / (1.0f + d);   // decay = sqrt(2*0.5) = 1
        }
        for (int i = 0; i < 15; ++i) {
            const int q  = g + 8 * i;
            const int ei = 3 * (int)c_I[q], ej = 3 * (int)c_J[q];
            const float dx = myrs[ei + 0] - myrs[ej + 0];
            const float dy = myrs[ei + 1] - myrs[ej + 1];
            const float dz = myrs[ei + 2] - myrs[ej + 2];
            dst[64 + q] = sqrtf(dx * dx + dy * dy + dz * dz);
        }
    }
    __syncthreads();

    // per-lane Gaussian constants: x = 2^(-(d*P1+P0)^2), S = sqrt(log2 e)
    const int f0 = lh * 8;
#define MKC(P, FF) float P##1, P##0; { \
    const float fq = (float)(FF) * (1.0f / 31.0f); \
    const float mu = 10.0f * fq * fq; \
    const float is = 7.0f / (1.0f + 10.0f * fq); \
    P##1 = is * 1.2011224087864498f; \
    P##0 = -mu * P##1; }
    MKC(C0_, f0 + 0) MKC(C1_, f0 + 1) MKC(C2_, f0 + 2) MKC(C3_, f0 + 3)
    MKC(C4_, f0 + 4) MKC(C5_, f0 + 5) MKC(C6_, f0 + 6) MKC(C7_, f0 + 7)
    MKC(D0_, f0 + 16) MKC(D1_, f0 + 17) MKC(D2_, f0 + 18) MKC(D3_, f0 + 19)
    MKC(D4_, f0 + 20) MKC(D5_, f0 + 21) MKC(D6_, f0 + 22) MKC(D7_, f0 + 23)
#undef MKC

    // ---- K loop: 46 pairs, unroll x2, dual fragment sets, no barriers ----
    floatx16 accA = {};   // cols 0..31
    floatx16 accB = {};   // cols 32..63
    const half8* wq = ws + ((size_t)(wave * KP) * 256 + lane);
    const float* drow = lds_dist + m * DLD + wave * KP;

#define XT(P) ({ const float t_ = fmaf(d, P##1, P##0); exp2_raw(t_ * -t_); })
#define KROUND(dd, Q0, Q1, Q2, Q3) { \
    const float d = (dd); \
    union { half8 v; fp16x2 h[4]; } ua, ub; \
    ua.h[0] = __builtin_amdgcn_cvt_pkrtz(XT(C0_), XT(C1_)); \
    ua.h[1] = __builtin_amdgcn_cvt_pkrtz(XT(C2_), XT(C3_)); \
    ua.h[2] = __builtin_amdgcn_cvt_pkrtz(XT(C4_), XT(C5_)); \
    ua.h[3] = __builtin_amdgcn_cvt_pkrtz(XT(C6_), XT(C7_)); \
    ub.h[0] = __builtin_amdgcn_cvt_pkrtz(XT(D0_), XT(D1_)); \
    ub.h[1] = __builtin_amdgcn_cvt_pkrtz(XT(D2_), XT(D3_)); \
    ub.h[2] = __builtin_amdgcn_cvt_pkrtz(XT(D4_), XT(D5_)); \
    ub.h[3] = __builtin_amdgcn_cvt_pkrtz(XT(D6_), XT(D7_)); \
    accA = __builtin_amdgcn_mfma_f32_32x32x16_f16(ua.v, Q0, accA, 0, 0, 0); \
    accB = __builtin_amdgcn_mfma_f32_32x32x16_f16(ua.v, Q1, accB, 0, 0, 0); \
    accA = __builtin_amdgcn_mfma_f32_32x32x16_f16(ub.v, Q2, accA, 0, 0, 0); \
    accB = __builtin_amdgcn_mfma_f32_32x32x16_f16(ub.v, Q3, accB, 0, 0, 0); \
}

    half8 pA0 = wq[0],   pA1 = wq[64],  pA2 = wq[128], pA3 = wq[192];
    half8 pB0 = wq[256], pB1 = wq[320], pB2 = wq[384], pB3 = wq[448];
    float d0 = drow[0], d1 = drow[1];

    for (int it = 0; it < 22; ++it) {       // rounds 0..43 with prefetch
        const float d0n = drow[2 * it + 2];
        const float d1n = drow[2 * it + 3];
        const half8* wn = wq + 512;

        KROUND(d0, pA0, pA1, pA2, pA3);     // even round 2it
        pA0 = wn[0];  pA1 = wn[64];  pA2 = wn[128]; pA3 = wn[192];

        KROUND(d1, pB0, pB1, pB2, pB3);     // odd round 2it+1
        pB0 = wn[256]; pB1 = wn[320]; pB2 = wn[384]; pB3 = wn[448];

        wq = wn;
        d0 = d0n; d1 = d1n;
    }
    KROUND(d0, pA0, pA1, pA2, pA3);         // round 44, no prefetch
    KROUND(d1, pB0, pB1, pB2, pB3);         // round 45
#undef KROUND
#undef XT

    __syncthreads();   // all K-loops done -> dist region reused as red/h1
    float* lds_red = lds_dist;   // 16 KB red region + h1 live inside it

    // ---- kh reduction. C/D: col = lane&31 (+nh*32),
    //      row el = (rg&3) + 8*(rg>>2) + 4*lh ----
    if (wave >= 2) {
        float* dst = lds_red + (wave - 2) * 2048;
#pragma unroll
        for (int rg = 0; rg < 16; ++rg) {
            const int el = (rg & 3) + 8 * (rg >> 2) + 4 * lh;
            dst[el * 64 + m]      = accA[rg];
            dst[el * 64 + 32 + m] = accB[rg];
        }
    }
    __syncthreads();
    if (wave < 2) {
        const float* srcr = lds_red + wave * 2048;
#pragma unroll
        for (int rg = 0; rg < 16; ++rg) {
            const int el = (rg & 3) + 8 * (rg >> 2) + 4 * lh;
            accA[rg] += srcr[el * 64 + m];
            accB[rg] += srcr[el * 64 + 32 + m];
        }
    }
    __syncthreads();
    if (wave == 1) {
#pragma unroll
        for (int rg = 0; rg < 16; ++rg) {
            const int el = (rg & 3) + 8 * (rg >> 2) + 4 * lh;
            lds_red[el * 64 + m]      = accA[rg];
            lds_red[el * 64 + 32 + m] = accB[rg];
        }
    }
    __syncthreads();
    if (wave == 0) {
        const float bA = b1[m], bB = b1[32 + m];
#pragma unroll
        for (int rg = 0; rg < 16; ++rg) {
            const int el = (rg & 3) + 8 * (rg >> 2) + 4 * lh;
            accA[rg] += lds_red[el * 64 + m];
            accB[rg] += lds_red[el * 64 + 32 + m];
        }
        // wave-0 LDS ops are in-order: reads above retire before these writes
#pragma unroll
        for (int rg = 0; rg < 16; ++rg) {
            const int el = (rg & 3) + 8 * (rg >> 2) + 4 * lh;
            lds_red[el * H1LD + m]      = ssp(accA[rg] + bA);
            lds_red[el * H1LD + 32 + m] = ssp(accB[rg] + bB);
        }
    }
    __syncthreads();

    // ---- tail: layers 2/3 (asy already in a register) ----
    const int b_local = tid >> 3;
    const int g       = tid & 7;
    const int b       = blockIdx.x * TB + b_local;
    asy = redg(asy);

    const float4* __restrict__ W2v = (const float4*)W2;
    const float4* __restrict__ b2v = (const float4*)b2;
    const int wbi = g * 2;
    const float4 b2a = b2v[wbi], b2b = b2v[wbi + 1];
    float s0 = b2a.x, s1 = b2a.y, s2 = b2a.z, s3 = b2a.w;
    float s4 = b2b.x, s5 = b2b.y, s6 = b2b.z, s7 = b2b.w;

    const float* __restrict__ h1row = lds_red + b_local * H1LD;
    for (int k = 0; k < HIDDEN; ++k) {
        const float hk  = h1row[k];
        const float4 wa = W2v[k * 16 + wbi];
        const float4 wb = W2v[k * 16 + wbi + 1];
        s0 = fmaf(hk, wa.x, s0); s1 = fmaf(hk, wa.y, s1);
        s2 = fmaf(hk, wa.z, s2); s3 = fmaf(hk, wa.w, s3);
        s4 = fmaf(hk, wb.x, s4); s5 = fmaf(hk, wb.y, s5);
        s6 = fmaf(hk, wb.z, s6); s7 = fmaf(hk, wb.w, s7);
    }

    const float4* __restrict__ W3v = (const float4*)W3;
    const float4 w3a = W3v[wbi], w3b = W3v[wbi + 1];
    float part = ssp(s0) * w3a.x + ssp(s1) * w3a.y
               + ssp(s2) * w3a.z + ssp(s3) * w3a.w
               + ssp(s4) * w3b.x + ssp(s5) * w3b.y
               + ssp(s6) * w3b.z + ssp(s7) * w3b.w;
    part = redg(part);

    if (g == 0) {
        const float ys = part + b3[0];
        out[b] = __expf(ys) * __expf(-asy);
    }
}

extern "C" void kernel_launch(void* const* d_in, const int* in_sizes, int n_in,
                              void* d_out, int out_size, void* d_ws, size_t ws_size,
                              hipStream_t stream) {
    const float* rs      = (const float*)d_in[0];
    const float* coords  = (const float*)d_in[1];
    const float* charges = (const float*)d_in[2];
    const float* W1      = (const float*)d_in[3];
    const float* b1      = (const float*)d_in[4];
    const float* W2      = (const float*)d_in[5];
    const float* b2      = (const float*)d_in[6];
    const float* W3      = (const float*)d_in[7];
    const float* b3      = (const float*)d_in[8];
    float* out = (float*)d_out;

    const int batch = in_sizes[0] / (N_EL * 3);   // 32768
    half8* ws = (half8*)d_ws;                     // 736 KB scratch

    prep_w1_kernel<<<N_PAIRS, 256, 0, stream>>>(W1, ws);
    wfnet_kernel<<<batch / TB, BLOCK, 0, stream>>>(rs, coords, charges, ws,
                                                   b1, W2, b2, W3, b3, out);
}